// Round 2
// baseline (12572.060 us; speedup 1.0000x reference)
//
#include <hip/hip_runtime.h>
#include <math.h>

#define B_   8
#define C_   96
#define C2_  192
#define N_   3136        // 56*56
#define R_   25088       // B_*N_
#define SEG_ 8
#define SEGLEN_ 392      // N_/SEG_
#define TM2_ 56          // fp64 candidate tile (392 = 7*56)
#define OUP_ 192
#define HO_  28
#define NO_  784         // 28*28
#define EPS_ 1e-5f

// ---------------- fc1 (fp64 accumulate): yd[b,d,n] = sum_c x[b,c,n]*W1[c,d] + b1[d] ----------------
__global__ __launch_bounds__(512) void k_fc1_d(const float* __restrict__ x,
                                               const float* __restrict__ W1,
                                               const float* __restrict__ b1,
                                               double* __restrict__ yd) {
    __shared__ double Wl[96 * 48];
    int tid = threadIdx.x;
    int rl = tid & 255, h = tid >> 8;     // h in 0..1
    int dbase = blockIdx.y * 48;          // block covers 48 output channels
    for (int q = tid; q < 96 * 48; q += 512) {
        int c = q / 48, dd = q % 48;
        Wl[c * 48 + dd] = (double)W1[c * 96 + dbase + dd];
    }
    __syncthreads();
    int r = blockIdx.x * 256 + rl;        // 98*256 == 25088 exact
    int b = r / N_;
    int n = r - b * N_;
    double acc[24];
#pragma unroll
    for (int i = 0; i < 24; i++) acc[i] = 0.0;
    const float* xp = x + (size_t)b * C_ * N_ + n;
    for (int c = 0; c < 96; ++c) {
        double xv = (double)xp[(size_t)c * N_];
        const double* w = &Wl[c * 48 + h * 24];
#pragma unroll
        for (int i = 0; i < 24; ++i) acc[i] += xv * w[i];
    }
    int d0 = dbase + h * 24;
#pragma unroll
    for (int i = 0; i < 24; i++) {
        int d = d0 + i;
        yd[((size_t)b * C_ + d) * N_ + n] = acc[i] + (double)b1[d];
    }
}

// ---------------- fp64 per-channel stats over yd (B,C,N) ----------------
__global__ __launch_bounds__(256) void k_stats_chan_d(const double* __restrict__ src,
                                                      double* __restrict__ partial) {
    int c = blockIdx.x;
    int chunk = blockIdx.y;
    const int SPLIT = 16;
    double s = 0.0, ss = 0.0;
    for (int j = chunk * 256 + threadIdx.x; j < R_; j += SPLIT * 256) {
        int b = j / N_, n = j - b * N_;
        double v = src[((size_t)b * C_ + c) * N_ + n];
        s += v;
        ss += v * v;
    }
    __shared__ double red[8];
    for (int off = 32; off; off >>= 1) {
        s += __shfl_down(s, off, 64);
        ss += __shfl_down(ss, off, 64);
    }
    int lane = threadIdx.x & 63, w = threadIdx.x >> 6;
    if (lane == 0) { red[w * 2] = s; red[w * 2 + 1] = ss; }
    __syncthreads();
    if (threadIdx.x == 0) {
        s = red[0] + red[2] + red[4] + red[6];
        ss = red[1] + red[3] + red[5] + red[7];
        partial[(c * SPLIT + chunk) * 2] = s;
        partial[(c * SPLIT + chunk) * 2 + 1] = ss;
    }
}

__global__ void k_stats_reduce_d(const double* __restrict__ partial, double* __restrict__ stats) {
    int c = blockIdx.x * blockDim.x + threadIdx.x;
    if (c >= 96) return;
    double s = 0.0, ss = 0.0;
    for (int k = 0; k < 16; k++) {
        s += partial[(c * 16 + k) * 2];
        ss += partial[(c * 16 + k) * 2 + 1];
    }
    double m = s / (double)R_;
    double var = ss / (double)R_ - m * m;
    stats[c * 2] = m;
    stats[c * 2 + 1] = 1.0 / sqrt(var + 1e-5);
}

// ---------------- fp32 per-channel stats (B, C, Nsp) ----------------
__global__ __launch_bounds__(256) void k_stats_chan(const float* __restrict__ src,
                                                    float* __restrict__ partial,
                                                    int Cn, int Nsp, int total) {
    int c = blockIdx.x;
    int chunk = blockIdx.y;
    int SPLIT = gridDim.y;
    float s = 0.f, ss = 0.f;
    for (int j = chunk * 256 + threadIdx.x; j < total; j += SPLIT * 256) {
        int b = j / Nsp, n = j - b * Nsp;
        float v = src[((size_t)b * Cn + c) * Nsp + n];
        s += v;
        ss += v * v;
    }
    __shared__ float red[8];
    for (int off = 32; off; off >>= 1) {
        s += __shfl_down(s, off, 64);
        ss += __shfl_down(ss, off, 64);
    }
    int lane = threadIdx.x & 63, w = threadIdx.x >> 6;
    if (lane == 0) { red[w * 2] = s; red[w * 2 + 1] = ss; }
    __syncthreads();
    if (threadIdx.x == 0) {
        s = red[0] + red[2] + red[4] + red[6];
        ss = red[1] + red[3] + red[5] + red[7];
        partial[(c * SPLIT + chunk) * 2] = s;
        partial[(c * SPLIT + chunk) * 2 + 1] = ss;
    }
}

__global__ void k_stats_reduce(const float* __restrict__ partial, float* __restrict__ stats,
                               int Cn, int SPLIT, float invcount) {
    int c = blockIdx.x * blockDim.x + threadIdx.x;
    if (c >= Cn) return;
    float s = 0.f, ss = 0.f;
    for (int k = 0; k < SPLIT; k++) {
        s += partial[(c * SPLIT + k) * 2];
        ss += partial[(c * SPLIT + k) * 2 + 1];
    }
    float m = s * invcount;
    float var = ss * invcount - m * m;
    stats[c * 2] = m;
    stats[c * 2 + 1] = 1.0f / sqrtf(var + EPS_);
}

// reduce for k_bne_stats partial layout
__global__ void k_stats_reduce_b(const float* __restrict__ partial, float* __restrict__ stats,
                                 int Cn, int NB, float invcount) {
    int c = blockIdx.x * blockDim.x + threadIdx.x;
    if (c >= Cn) return;
    float s = 0.f, ss = 0.f;
    for (int k = 0; k < NB; k++) {
        s += partial[(size_t)k * 2 * Cn + c];
        ss += partial[(size_t)k * 2 * Cn + Cn + c];
    }
    float m = s * invcount;
    float var = ss * invcount - m * m;
    stats[c * 2] = m;
    stats[c * 2 + 1] = 1.0f / sqrtf(var + EPS_);
}

// ---------------- apply BN1 (fp64); emit ftc (f32 ch-major), ftp32/ftp64 (point-major) ----------------
__global__ __launch_bounds__(256) void k_bn1_apply_d(const double* __restrict__ yd,
                                                     const double* __restrict__ stats,
                                                     const float* __restrict__ g,
                                                     const float* __restrict__ be,
                                                     float* __restrict__ ftc,
                                                     float* __restrict__ ftp32,
                                                     double* __restrict__ ftp64) {
    int i = blockIdx.x * 256 + threadIdx.x;
    if (i >= B_ * C_ * N_) return;
    int n = i % N_;
    int bc = i / N_;
    int c = bc % C_;
    int b = bc / C_;
    double m = stats[c * 2], rs = stats[c * 2 + 1];
    double v = (double)g[c] * (yd[i] - m) * rs + (double)be[c];
    float vf = (float)v;
    ftc[i] = vf;
    size_t pp = ((size_t)b * N_ + n) * C_ + c;
    ftp32[pp] = vf;
    ftp64[pp] = v;
}

__global__ __launch_bounds__(256) void k_sqrows_d(const double* __restrict__ ftp64, double* __restrict__ sq) {
    int r = blockIdx.x * 256 + threadIdx.x;
    if (r >= R_) return;
    const double* p = ftp64 + (size_t)r * C_;
    double s = 0.0;
    for (int q = 0; q < 96; q++) s += p[q] * p[q];
    sq[r] = s;
}

// ---------------- fp64 distance + per-segment top-9 ----------------
__global__ __launch_bounds__(256) void k_dist_topk_d(const float* __restrict__ ftp32,
                                                     const double* __restrict__ ftp64,
                                                     const double* __restrict__ sq,
                                                     double* __restrict__ cd,
                                                     int* __restrict__ ci) {
    __shared__ double tile[TM2_ * C_];
    __shared__ double sqt[TM2_];
    int b = blockIdx.z, seg = blockIdx.y;
    int n = blockIdx.x * 256 + threadIdx.x;
    bool valid = n < N_;
    float4 rr[24];
    double sqn = 0.0;
    if (valid) {
        const float4* p = (const float4*)(ftp32 + ((size_t)b * N_ + n) * C_);
#pragma unroll
        for (int q = 0; q < 24; q++) rr[q] = p[q];
        sqn = sq[b * N_ + n];
    }
    double kd[9];
    int ki[9];
#pragma unroll
    for (int j = 0; j < 9; j++) { kd[j] = 1e300; ki[j] = 0x7fffffff; }

#define INSERT9(dv, iv)                                                     \
    if ((dv) < kd[8]) {                                                     \
        kd[8] = (dv); ki[8] = (iv);                                         \
        _Pragma("unroll")                                                   \
        for (int j = 8; j >= 1; --j) {                                      \
            if (kd[j] < kd[j - 1]) {                                        \
                double td = kd[j]; kd[j] = kd[j - 1]; kd[j - 1] = td;       \
                int ti = ki[j]; ki[j] = ki[j - 1]; ki[j - 1] = ti;          \
            }                                                               \
        }                                                                   \
    }

    for (int t = 0; t < 7; ++t) {
        int m0 = seg * SEGLEN_ + t * TM2_;
        const double2* src = (const double2*)(ftp64 + ((size_t)b * N_ + m0) * C_);
        double2* dst = (double2*)tile;
        for (int q = threadIdx.x; q < TM2_ * 48; q += 256) dst[q] = src[q];
        if (threadIdx.x < TM2_) sqt[threadIdx.x] = sq[b * N_ + m0 + threadIdx.x];
        __syncthreads();
        if (valid) {
            for (int g4 = 0; g4 < TM2_ / 4; ++g4) {
                const double* t0 = &tile[(g4 * 4 + 0) * C_];
                const double* t1 = t0 + C_;
                const double* t2 = t0 + 2 * C_;
                const double* t3 = t0 + 3 * C_;
                double a0 = 0.0, a1 = 0.0, a2 = 0.0, a3 = 0.0;
#pragma unroll
                for (int q = 0; q < 24; ++q) {
                    float4 rv = rr[q];
                    double r0 = (double)rv.x, r1 = (double)rv.y, r2 = (double)rv.z, r3 = (double)rv.w;
                    a0 += r0 * t0[q * 4 + 0]; a0 += r1 * t0[q * 4 + 1];
                    a0 += r2 * t0[q * 4 + 2]; a0 += r3 * t0[q * 4 + 3];
                    a1 += r0 * t1[q * 4 + 0]; a1 += r1 * t1[q * 4 + 1];
                    a1 += r2 * t1[q * 4 + 2]; a1 += r3 * t1[q * 4 + 3];
                    a2 += r0 * t2[q * 4 + 0]; a2 += r1 * t2[q * 4 + 1];
                    a2 += r2 * t2[q * 4 + 2]; a2 += r3 * t2[q * 4 + 3];
                    a3 += r0 * t3[q * 4 + 0]; a3 += r1 * t3[q * 4 + 1];
                    a3 += r2 * t3[q * 4 + 2]; a3 += r3 * t3[q * 4 + 3];
                }
                int mb = m0 + g4 * 4;
                double d0v = sqn - 2.0 * a0 + sqt[g4 * 4 + 0];
                INSERT9(d0v, mb + 0);
                double d1v = sqn - 2.0 * a1 + sqt[g4 * 4 + 1];
                INSERT9(d1v, mb + 1);
                double d2v = sqn - 2.0 * a2 + sqt[g4 * 4 + 2];
                INSERT9(d2v, mb + 2);
                double d3v = sqn - 2.0 * a3 + sqt[g4 * 4 + 3];
                INSERT9(d3v, mb + 3);
            }
        }
        __syncthreads();
    }
    if (valid) {
        size_t base = (((size_t)b * N_ + n) * SEG_ + seg) * 9;
#pragma unroll
        for (int j = 0; j < 9; j++) { cd[base + j] = kd[j]; ci[base + j] = ki[j]; }
    }
}

__global__ __launch_bounds__(256) void k_topk_merge_d(const double* __restrict__ cd,
                                                      const int* __restrict__ ci,
                                                      int* __restrict__ idx) {
    int r = blockIdx.x * 256 + threadIdx.x;
    if (r >= R_) return;
    double kd[9];
    int ki[9];
#pragma unroll
    for (int j = 0; j < 9; j++) { kd[j] = 1e300; ki[j] = 0x7fffffff; }
    for (int q = 0; q < SEG_ * 9; ++q) {   // segments in ascending index order
        double d = cd[(size_t)r * 72 + q];
        int i = ci[(size_t)r * 72 + q];
        INSERT9(d, i);
    }
#pragma unroll
    for (int j = 0; j < 9; j++) idx[(size_t)r * 9 + j] = ki[j];
}

// ---------------- u = ft·(Wtop-Wbot) + b_edge (mode 0), v = ft·Wbot (mode 1) ----------------
__global__ __launch_bounds__(512) void k_gemm_uv(const float* __restrict__ ftc,
                                                 const float* __restrict__ We,
                                                 const float* __restrict__ beb,
                                                 float* __restrict__ out, int mode) {
    __shared__ float Wl[96 * 48];
    int tid = threadIdx.x;
    int rl = tid & 255, h = tid >> 8;
    int dbase = blockIdx.y * 48;
    for (int q = tid; q < 96 * 48; q += 512) {
        int c = q / 48, dd = q % 48;
        float w = We[(96 + c) * C2_ + dbase + dd];
        if (mode == 0) w = We[c * C2_ + dbase + dd] - w;
        Wl[c * 48 + dd] = w;
    }
    __syncthreads();
    int r = blockIdx.x * 256 + rl;
    int b = r / N_, n = r - b * N_;
    float acc[24];
#pragma unroll
    for (int i = 0; i < 24; i++) acc[i] = 0.f;
    const float* xp = ftc + (size_t)b * C_ * N_ + n;
    for (int c = 0; c < 96; ++c) {
        float xv = xp[(size_t)c * N_];
        const float4* w4 = (const float4*)&Wl[c * 48 + h * 24];
#pragma unroll
        for (int i = 0; i < 6; ++i) {
            float4 w = w4[i];
            acc[i * 4 + 0] += xv * w.x;
            acc[i * 4 + 1] += xv * w.y;
            acc[i * 4 + 2] += xv * w.z;
            acc[i * 4 + 3] += xv * w.w;
        }
    }
    int d0 = dbase + h * 24;
    float* op = out + (size_t)r * C2_ + d0;
#pragma unroll
    for (int i = 0; i < 6; ++i) {
        float4 o;
        o.x = acc[i * 4 + 0]; o.y = acc[i * 4 + 1];
        o.z = acc[i * 4 + 2]; o.w = acc[i * 4 + 3];
        if (mode == 0) {
            o.x += beb[d0 + i * 4 + 0];
            o.y += beb[d0 + i * 4 + 1];
            o.z += beb[d0 + i * 4 + 2];
            o.w += beb[d0 + i * 4 + 3];
        }
        ((float4*)op)[i] = o;
    }
}

// ---------------- edge-BN stats: e = u[n,d] + v[j,d] over all (row,k) ----------------
__global__ __launch_bounds__(192) void k_bne_stats(const float* __restrict__ u,
                                                   const float* __restrict__ v,
                                                   const int* __restrict__ idx,
                                                   float* __restrict__ partial) {
    int d = threadIdx.x;
    int row0 = blockIdx.x * 32;
    int b = row0 / N_;
    float s = 0.f, ss = 0.f;
    for (int r = 0; r < 32; ++r) {
        int row = row0 + r;
        float ud = u[(size_t)row * C2_ + d];
        const int* ip = idx + (size_t)row * 9;
#pragma unroll
        for (int k = 0; k < 9; k++) {
            int j = ip[k];
            float e = ud + v[((size_t)b * N_ + j) * C2_ + d];
            s += e;
            ss += e * e;
        }
    }
    partial[(size_t)blockIdx.x * 384 + d] = s;
    partial[(size_t)blockIdx.x * 384 + 192 + d] = ss;
}

// ---------------- edge BN+relu+max over k, then fc2 (192->96) ----------------
__global__ __launch_bounds__(192) void k_edge_fc2(const float* __restrict__ u,
                                                  const float* __restrict__ v,
                                                  const int* __restrict__ idx,
                                                  const float* __restrict__ statsE,
                                                  const float* __restrict__ ge,
                                                  const float* __restrict__ bee,
                                                  const float* __restrict__ W2,
                                                  const float* __restrict__ b2,
                                                  float* __restrict__ out2) {
    __shared__ float gl[16][C2_];
    __shared__ float g2[C_][16];
    int tid = threadIdx.x;
    int row0 = blockIdx.x * 16;
    int b = row0 / N_;
    int n0 = row0 - b * N_;
    {
        int d = tid;
        float m = statsE[d * 2], rs = statsE[d * 2 + 1];
        float ga = ge[d], bb = bee[d];
        for (int r = 0; r < 16; ++r) {
            int row = row0 + r;
            float ud = u[(size_t)row * C2_ + d];
            const int* ip = idx + (size_t)row * 9;
            float gm = 0.f;                      // relu-then-max == max with 0
#pragma unroll
            for (int k = 0; k < 9; k++) {
                int j = ip[k];
                float e = ud + v[((size_t)b * N_ + j) * C2_ + d];
                float val = ga * (e - m) * rs + bb;
                gm = fmaxf(gm, val);
            }
            gl[r][d] = gm;
        }
    }
    __syncthreads();
    {
        int rr = tid / 24;     // 0..7
        int dq = tid % 24;     // float4 column group
        for (int rep = 0; rep < 2; ++rep) {
            int r = rr + rep * 8;
            float4 acc = *(const float4*)&b2[dq * 4];
            for (int d = 0; d < C2_; ++d) {
                float gv = gl[r][d];
                float4 w = *(const float4*)&W2[d * C_ + dq * 4];
                acc.x += gv * w.x;
                acc.y += gv * w.y;
                acc.z += gv * w.z;
                acc.w += gv * w.w;
            }
            g2[dq * 4 + 0][r] = acc.x;
            g2[dq * 4 + 1][r] = acc.y;
            g2[dq * 4 + 2][r] = acc.z;
            g2[dq * 4 + 3][r] = acc.w;
        }
    }
    __syncthreads();
    for (int q = tid; q < 96 * 4; q += 192) {
        int dd = q / 4, part = q % 4;
        float4 val = *(const float4*)&g2[dd][part * 4];
        *(float4*)&out2[((size_t)b * C_ + dd) * N_ + n0 + part * 4] = val;
    }
}

// ---------------- t = bn2(out2) + x ----------------
__global__ __launch_bounds__(256) void k_bn2_add(const float* __restrict__ out2,
                                                 const float* __restrict__ x,
                                                 const float* __restrict__ stats,
                                                 const float* __restrict__ g,
                                                 const float* __restrict__ be,
                                                 float* __restrict__ t) {
    int i = blockIdx.x * 256 + threadIdx.x;
    if (i >= B_ * C_ * N_) return;
    int c = (i / N_) % C_;
    t[i] = g[c] * (out2[i] - stats[c * 2]) * stats[c * 2 + 1] + be[c] + x[i];
}

// ---------------- s = relu(sabn(t)) ----------------
__global__ __launch_bounds__(256) void k_sabn_relu(const float* __restrict__ t,
                                                   const float* __restrict__ stats,
                                                   const float* __restrict__ g,
                                                   const float* __restrict__ be,
                                                   float* __restrict__ s) {
    int i = blockIdx.x * 256 + threadIdx.x;
    if (i >= B_ * C_ * N_) return;
    int c = (i / N_) % C_;
    s[i] = fmaxf(g[c] * (t[i] - stats[c * 2]) * stats[c * 2 + 1] + be[c], 0.f);
}

// ---------------- conv 3x3 stride 2 pad 1, 96->192 ----------------
__global__ __launch_bounds__(256) void k_conv(const float* __restrict__ s,
                                              const float* __restrict__ Wd,
                                              const float* __restrict__ bd,
                                              float* __restrict__ z) {
    __shared__ float Wl[96 * 9 * 16];
    int b = blockIdx.z;
    int oc0 = blockIdx.y * 16;
    int p = blockIdx.x * 256 + threadIdx.x;
    for (int i = threadIdx.x; i < 96 * 9 * 16; i += 256) {
        int oc = i & 15;
        int icq = i >> 4;
        Wl[i] = Wd[(size_t)(oc0 + oc) * 864 + icq];
    }
    __syncthreads();
    if (p >= NO_) return;
    int oh = p / HO_, ow = p % HO_;
    float acc[16];
#pragma unroll
    for (int i = 0; i < 16; i++) acc[i] = 0.f;
    int ih0 = oh * 2 - 1, iw0 = ow * 2 - 1;
    const float* sb = s + (size_t)b * C_ * N_;
    for (int ic = 0; ic < 96; ++ic) {
        const float* sp = sb + (size_t)ic * N_;
        float in[9];
#pragma unroll
        for (int kh = 0; kh < 3; kh++) {
            int ih = ih0 + kh;
            bool okh = (unsigned)ih < 56u;
#pragma unroll
            for (int kw = 0; kw < 3; kw++) {
                int iw = iw0 + kw;
                bool ok = okh && ((unsigned)iw < 56u);
                in[kh * 3 + kw] = ok ? sp[ih * 56 + iw] : 0.f;
            }
        }
#pragma unroll
        for (int q = 0; q < 9; q++) {
            float iv = in[q];
            const float4* w4 = (const float4*)&Wl[(ic * 9 + q) * 16];
#pragma unroll
            for (int j = 0; j < 4; j++) {
                float4 w = w4[j];
                acc[j * 4 + 0] += iv * w.x;
                acc[j * 4 + 1] += iv * w.y;
                acc[j * 4 + 2] += iv * w.z;
                acc[j * 4 + 3] += iv * w.w;
            }
        }
    }
#pragma unroll
    for (int i = 0; i < 16; i++)
        z[((size_t)b * OUP_ + oc0 + i) * NO_ + p] = acc[i] + bd[oc0 + i];
}

// ---------------- out = relu(dwbn(z)) ----------------
__global__ __launch_bounds__(256) void k_out(const float* __restrict__ z,
                                             const float* __restrict__ stats,
                                             const float* __restrict__ g,
                                             const float* __restrict__ be,
                                             float* __restrict__ out) {
    int i = blockIdx.x * 256 + threadIdx.x;
    if (i >= B_ * OUP_ * NO_) return;
    int c = (i / NO_) % OUP_;
    out[i] = fmaxf(g[c] * (z[i] - stats[c * 2]) * stats[c * 2 + 1] + be[c], 0.f);
}

extern "C" void kernel_launch(void* const* d_in, const int* in_sizes, int n_in,
                              void* d_out, int out_size, void* d_ws, size_t ws_size,
                              hipStream_t stream) {
    const float* x     = (const float*)d_in[0];
    const float* W_fc1 = (const float*)d_in[1];
    const float* b_fc1 = (const float*)d_in[2];
    const float* g_bn1 = (const float*)d_in[3];
    const float* be_bn1= (const float*)d_in[4];
    const float* W_edge= (const float*)d_in[5];
    const float* b_edge= (const float*)d_in[6];
    const float* g_bne = (const float*)d_in[7];
    const float* be_bne= (const float*)d_in[8];
    const float* W_fc2 = (const float*)d_in[9];
    const float* b_fc2 = (const float*)d_in[10];
    const float* g_bn2 = (const float*)d_in[11];
    const float* be_bn2= (const float*)d_in[12];
    const float* g_sabn= (const float*)d_in[13];
    const float* be_sabn=(const float*)d_in[14];
    const float* W_dw  = (const float*)d_in[15];
    const float* b_dw  = (const float*)d_in[16];
    const float* g_dwbn= (const float*)d_in[17];
    const float* be_dwbn=(const float*)d_in[18];

    // byte-offset workspace layout with lifetime-based aliasing (~106 MB)
    char* base = (char*)d_ws;
    float*  ftc   = (float*)(base + 0);                    //  9,633,792  [bn1 -> gemms]
    float*  ftp32 = (float*)(base + 9633792);              //  9,633,792  [bn1 -> dist]
    double* ftp64 = (double*)(base + 19267584);            // 19,267,584  [bn1 -> dist]
    double* sq64  = (double*)(base + 38535168);            //    200,704
    double* yd    = (double*)(base + 38735872);            // 19,267,584  [fc1 -> bn1]
    double* cd    = (double*)(base + 38735872);            // 14,450,688  [dist -> merge]  (aliases yd)
    float*  out2  = (float*)(base + 38735872);             //  9,633,792  [edge_fc2 -> bn2] (aliases yd/cd)
    int*    ci    = (int*)(base + 58003456);               //  7,225,344  [dist -> merge]
    float*  zbuf  = (float*)(base + 58003456);             //  4,816,896  [conv -> out]   (aliases ci)
    int*    idx   = (int*)(base + 65228800);               //    903,168  [merge -> edge_fc2]
    float*  uu    = (float*)(base + 19267584);             // 19,267,584  [gemm -> edge_fc2] (aliases ftp64)
    float*  vv    = (float*)(base + 66131968);             // 19,267,584  [gemm -> edge_fc2]
    float*  tbuf  = (float*)(base + 9633792);              //  9,633,792  [bn2 -> sabn]  (aliases ftp32)
    float*  sbuf  = (float*)(base + 0);                    //  9,633,792  [sabn -> conv] (aliases ftc)
    float*  partial = (float*)(base + 85399552);           //  1,204,224 max
    double* partiald = (double*)(base + 85399552);         //     24,576 (same region, earlier use)
    double* stats1d = (double*)(base + 86603776);          //      1,536
    float*  statsE  = (float*)(base + 86605312);
    float*  stats2  = statsE + 384;
    float*  statsS  = stats2 + 384;
    float*  statsD  = statsS + 384;

    // fc1 + BN1 (fp64 path)
    k_fc1_d<<<dim3(98, 2), 512, 0, stream>>>(x, W_fc1, b_fc1, yd);
    k_stats_chan_d<<<dim3(96, 16), 256, 0, stream>>>(yd, partiald);
    k_stats_reduce_d<<<1, 256, 0, stream>>>(partiald, stats1d);
    k_bn1_apply_d<<<9408, 256, 0, stream>>>(yd, stats1d, g_bn1, be_bn1, ftc, ftp32, ftp64);
    k_sqrows_d<<<98, 256, 0, stream>>>(ftp64, sq64);

    // kNN (fp64-exact set)
    k_dist_topk_d<<<dim3(13, SEG_, B_), 256, 0, stream>>>(ftp32, ftp64, sq64, cd, ci);
    k_topk_merge_d<<<98, 256, 0, stream>>>(cd, ci, idx);

    // edge GEMM decomposition: u = ft·(Wtop-Wbot)+b_edge, v = ft·Wbot
    k_gemm_uv<<<dim3(98, 4), 512, 0, stream>>>(ftc, W_edge, b_edge, uu, 0);
    k_gemm_uv<<<dim3(98, 4), 512, 0, stream>>>(ftc, W_edge, b_edge, vv, 1);

    // edge BN stats, then BN+relu+max+fc2
    k_bne_stats<<<784, 192, 0, stream>>>(uu, vv, idx, partial);
    k_stats_reduce_b<<<1, 256, 0, stream>>>(partial, statsE, 192, 784, 1.0f / 225792.0f);
    k_edge_fc2<<<1568, 192, 0, stream>>>(uu, vv, idx, statsE, g_bne, be_bne, W_fc2, b_fc2, out2);

    // BN2 + shortcut
    k_stats_chan<<<dim3(96, 16), 256, 0, stream>>>(out2, partial, 96, N_, R_);
    k_stats_reduce<<<1, 256, 0, stream>>>(partial, stats2, 96, 16, 1.0f / (float)R_);
    k_bn2_add<<<9408, 256, 0, stream>>>(out2, x, stats2, g_bn2, be_bn2, tbuf);

    // sabn + relu
    k_stats_chan<<<dim3(96, 16), 256, 0, stream>>>(tbuf, partial, 96, N_, R_);
    k_stats_reduce<<<1, 256, 0, stream>>>(partial, statsS, 96, 16, 1.0f / (float)R_);
    k_sabn_relu<<<9408, 256, 0, stream>>>(tbuf, statsS, g_sabn, be_sabn, sbuf);

    // conv + dwbn + relu
    k_conv<<<dim3(4, 12, 8), 256, 0, stream>>>(sbuf, W_dw, b_dw, zbuf);
    k_stats_chan<<<dim3(192, 8), 256, 0, stream>>>(zbuf, partial, 192, NO_, 6272);
    k_stats_reduce<<<1, 256, 0, stream>>>(partial, statsD, 192, 8, 1.0f / 6272.0f);
    k_out<<<4705, 256, 0, stream>>>(zbuf, statsD, g_dwbn, be_dwbn, (float*)d_out);
}

// Round 3
// 1403.980 us; speedup vs baseline: 8.9546x; 8.9546x over previous
//
#include <hip/hip_runtime.h>
#include <math.h>

#define B_   8
#define C_   96
#define C2_  192
#define N_   3136        // 56*56
#define R_   25088       // B_*N_
#define SEG_ 8
#define SEGLEN_ 392      // N_/SEG_
#define TM_  98          // fp32 candidate tile (392 = 4*98)
#define TK_  12          // per-segment keep
#define CAND_ 96         // SEG_*TK_
#define RER_ 16          // fp64 re-rank pool
#define OUP_ 192
#define HO_  28
#define NO_  784         // 28*28
#define EPS_ 1e-5f

// generic strict-< sorted insertion (static unroll)
#define INSERTK(K, kd, ki, dv, iv, T)                                       \
    if ((dv) < kd[(K)-1]) {                                                 \
        kd[(K)-1] = (dv); ki[(K)-1] = (iv);                                 \
        _Pragma("unroll")                                                   \
        for (int j = (K)-1; j >= 1; --j) {                                  \
            if (kd[j] < kd[j - 1]) {                                        \
                T td = kd[j]; kd[j] = kd[j - 1]; kd[j - 1] = td;            \
                int ti = ki[j]; ki[j] = ki[j - 1]; ki[j - 1] = ti;          \
            }                                                               \
        }                                                                   \
    }

// ---------------- fc1 (fp64 accumulate): yd[b,d,n] = sum_c x[b,c,n]*W1[c,d] + b1[d] ----------------
__global__ __launch_bounds__(512) void k_fc1_d(const float* __restrict__ x,
                                               const float* __restrict__ W1,
                                               const float* __restrict__ b1,
                                               double* __restrict__ yd) {
    __shared__ double Wl[96 * 48];
    int tid = threadIdx.x;
    int rl = tid & 255, h = tid >> 8;     // h in 0..1
    int dbase = blockIdx.y * 48;          // block covers 48 output channels
    for (int q = tid; q < 96 * 48; q += 512) {
        int c = q / 48, dd = q % 48;
        Wl[c * 48 + dd] = (double)W1[c * 96 + dbase + dd];
    }
    __syncthreads();
    int r = blockIdx.x * 256 + rl;        // 98*256 == 25088 exact
    int b = r / N_;
    int n = r - b * N_;
    double acc[24];
#pragma unroll
    for (int i = 0; i < 24; i++) acc[i] = 0.0;
    const float* xp = x + (size_t)b * C_ * N_ + n;
    for (int c = 0; c < 96; ++c) {
        double xv = (double)xp[(size_t)c * N_];
        const double* w = &Wl[c * 48 + h * 24];
#pragma unroll
        for (int i = 0; i < 24; ++i) acc[i] += xv * w[i];
    }
    int d0 = dbase + h * 24;
#pragma unroll
    for (int i = 0; i < 24; i++) {
        int d = d0 + i;
        yd[((size_t)b * C_ + d) * N_ + n] = acc[i] + (double)b1[d];
    }
}

// ---------------- fp64 per-channel stats over yd (B,C,N) ----------------
__global__ __launch_bounds__(256) void k_stats_chan_d(const double* __restrict__ src,
                                                      double* __restrict__ partial) {
    int c = blockIdx.x;
    int chunk = blockIdx.y;
    const int SPLIT = 16;
    double s = 0.0, ss = 0.0;
    for (int j = chunk * 256 + threadIdx.x; j < R_; j += SPLIT * 256) {
        int b = j / N_, n = j - b * N_;
        double v = src[((size_t)b * C_ + c) * N_ + n];
        s += v;
        ss += v * v;
    }
    __shared__ double red[8];
    for (int off = 32; off; off >>= 1) {
        s += __shfl_down(s, off, 64);
        ss += __shfl_down(ss, off, 64);
    }
    int lane = threadIdx.x & 63, w = threadIdx.x >> 6;
    if (lane == 0) { red[w * 2] = s; red[w * 2 + 1] = ss; }
    __syncthreads();
    if (threadIdx.x == 0) {
        s = red[0] + red[2] + red[4] + red[6];
        ss = red[1] + red[3] + red[5] + red[7];
        partial[(c * SPLIT + chunk) * 2] = s;
        partial[(c * SPLIT + chunk) * 2 + 1] = ss;
    }
}

__global__ void k_stats_reduce_d(const double* __restrict__ partial, double* __restrict__ stats) {
    int c = blockIdx.x * blockDim.x + threadIdx.x;
    if (c >= 96) return;
    double s = 0.0, ss = 0.0;
    for (int k = 0; k < 16; k++) {
        s += partial[(c * 16 + k) * 2];
        ss += partial[(c * 16 + k) * 2 + 1];
    }
    double m = s / (double)R_;
    double var = ss / (double)R_ - m * m;
    stats[c * 2] = m;
    stats[c * 2 + 1] = 1.0 / sqrt(var + 1e-5);
}

// ---------------- fp32 per-channel stats (B, C, Nsp) ----------------
__global__ __launch_bounds__(256) void k_stats_chan(const float* __restrict__ src,
                                                    float* __restrict__ partial,
                                                    int Cn, int Nsp, int total) {
    int c = blockIdx.x;
    int chunk = blockIdx.y;
    int SPLIT = gridDim.y;
    float s = 0.f, ss = 0.f;
    for (int j = chunk * 256 + threadIdx.x; j < total; j += SPLIT * 256) {
        int b = j / Nsp, n = j - b * Nsp;
        float v = src[((size_t)b * Cn + c) * Nsp + n];
        s += v;
        ss += v * v;
    }
    __shared__ float red[8];
    for (int off = 32; off; off >>= 1) {
        s += __shfl_down(s, off, 64);
        ss += __shfl_down(ss, off, 64);
    }
    int lane = threadIdx.x & 63, w = threadIdx.x >> 6;
    if (lane == 0) { red[w * 2] = s; red[w * 2 + 1] = ss; }
    __syncthreads();
    if (threadIdx.x == 0) {
        s = red[0] + red[2] + red[4] + red[6];
        ss = red[1] + red[3] + red[5] + red[7];
        partial[(c * SPLIT + chunk) * 2] = s;
        partial[(c * SPLIT + chunk) * 2 + 1] = ss;
    }
}

__global__ void k_stats_reduce(const float* __restrict__ partial, float* __restrict__ stats,
                               int Cn, int SPLIT, float invcount) {
    int c = blockIdx.x * blockDim.x + threadIdx.x;
    if (c >= Cn) return;
    float s = 0.f, ss = 0.f;
    for (int k = 0; k < SPLIT; k++) {
        s += partial[(c * SPLIT + k) * 2];
        ss += partial[(c * SPLIT + k) * 2 + 1];
    }
    float m = s * invcount;
    float var = ss * invcount - m * m;
    stats[c * 2] = m;
    stats[c * 2 + 1] = 1.0f / sqrtf(var + EPS_);
}

// reduce for k_bne_stats partial layout
__global__ void k_stats_reduce_b(const float* __restrict__ partial, float* __restrict__ stats,
                                 int Cn, int NB, float invcount) {
    int c = blockIdx.x * blockDim.x + threadIdx.x;
    if (c >= Cn) return;
    float s = 0.f, ss = 0.f;
    for (int k = 0; k < NB; k++) {
        s += partial[(size_t)k * 2 * Cn + c];
        ss += partial[(size_t)k * 2 * Cn + Cn + c];
    }
    float m = s * invcount;
    float var = ss * invcount - m * m;
    stats[c * 2] = m;
    stats[c * 2 + 1] = 1.0f / sqrtf(var + EPS_);
}

// ---------------- apply BN1 (fp64); emit ftc (f32 ch-major), ftp32/ftp64 (point-major) ----------------
__global__ __launch_bounds__(256) void k_bn1_apply_d(const double* __restrict__ yd,
                                                     const double* __restrict__ stats,
                                                     const float* __restrict__ g,
                                                     const float* __restrict__ be,
                                                     float* __restrict__ ftc,
                                                     float* __restrict__ ftp32,
                                                     double* __restrict__ ftp64) {
    int i = blockIdx.x * 256 + threadIdx.x;
    if (i >= B_ * C_ * N_) return;
    int n = i % N_;
    int bc = i / N_;
    int c = bc % C_;
    int b = bc / C_;
    double m = stats[c * 2], rs = stats[c * 2 + 1];
    double v = (double)g[c] * (yd[i] - m) * rs + (double)be[c];
    float vf = (float)v;
    ftc[i] = vf;
    size_t pp = ((size_t)b * N_ + n) * C_ + c;
    ftp32[pp] = vf;
    ftp64[pp] = v;
}

// ---------------- row squared norms: fp64 exact + fp32 copy ----------------
__global__ __launch_bounds__(256) void k_sqrows_d(const double* __restrict__ ftp64,
                                                  double* __restrict__ sq64,
                                                  float* __restrict__ sq32) {
    int r = blockIdx.x * 256 + threadIdx.x;
    if (r >= R_) return;
    const double* p = ftp64 + (size_t)r * C_;
    double s = 0.0;
    for (int q = 0; q < 96; q++) s += p[q] * p[q];
    sq64[r] = s;
    sq32[r] = (float)s;
}

// ---------------- fp32 distance + per-segment top-12 ----------------
__global__ __launch_bounds__(256) void k_dist_topk_f(const float* __restrict__ ftp32,
                                                     const float* __restrict__ sq32,
                                                     float* __restrict__ cd,
                                                     int* __restrict__ ci) {
    __shared__ float tile[TM_ * C_];
    __shared__ float sqt[TM_];
    int b = blockIdx.z, seg = blockIdx.y;
    int n = blockIdx.x * 256 + threadIdx.x;
    bool valid = n < N_;
    float4 rr[24];
    float sqn = 0.f;
    if (valid) {
        const float4* p = (const float4*)(ftp32 + ((size_t)b * N_ + n) * C_);
#pragma unroll
        for (int q = 0; q < 24; q++) rr[q] = p[q];
        sqn = sq32[b * N_ + n];
    }
    float kd[TK_];
    int ki[TK_];
#pragma unroll
    for (int j = 0; j < TK_; j++) { kd[j] = 1e30f; ki[j] = 0x7fffffff; }

    for (int t = 0; t < 4; ++t) {
        int m0 = seg * SEGLEN_ + t * TM_;
        const float4* src = (const float4*)(ftp32 + ((size_t)b * N_ + m0) * C_);
        float4* dst = (float4*)tile;
        for (int q = threadIdx.x; q < TM_ * 24; q += 256) dst[q] = src[q];
        if (threadIdx.x < TM_) sqt[threadIdx.x] = sq32[b * N_ + m0 + threadIdx.x];
        __syncthreads();
        if (valid) {
            for (int mm = 0; mm < TM_; mm += 2) {
                const float4* tp0 = (const float4*)(tile + mm * C_);
                const float4* tp1 = (const float4*)(tile + (mm + 1) * C_);
                float a0 = 0.f, a1 = 0.f, a2 = 0.f, a3 = 0.f;
                float b0 = 0.f, b1v = 0.f, b2 = 0.f, b3 = 0.f;
#pragma unroll
                for (int q = 0; q < 24; ++q) {
                    float4 rv = rr[q];
                    float4 t0 = tp0[q];
                    float4 t1 = tp1[q];
                    a0 += rv.x * t0.x; a1 += rv.y * t0.y;
                    a2 += rv.z * t0.z; a3 += rv.w * t0.w;
                    b0 += rv.x * t1.x; b1v += rv.y * t1.y;
                    b2 += rv.z * t1.z; b3 += rv.w * t1.w;
                }
                float d0 = sqn - 2.f * ((a0 + a1) + (a2 + a3)) + sqt[mm];
                float d1 = sqn - 2.f * ((b0 + b1v) + (b2 + b3)) + sqt[mm + 1];
                INSERTK(TK_, kd, ki, d0, m0 + mm, float);
                INSERTK(TK_, kd, ki, d1, m0 + mm + 1, float);
            }
        }
        __syncthreads();
    }
    if (valid) {
        size_t base = ((size_t)b * N_ + n) * CAND_ + seg * TK_;
#pragma unroll
        for (int j = 0; j < TK_; j++) { cd[base + j] = kd[j]; ci[base + j] = ki[j]; }
    }
}

// ---------------- merge: fp32 top-16 of 96, fp64 re-rank -> exact top-9 ----------------
__global__ __launch_bounds__(256) void k_merge_rerank(const float* __restrict__ cd,
                                                      const int* __restrict__ ci,
                                                      const double* __restrict__ ftp64,
                                                      const double* __restrict__ sq64,
                                                      int* __restrict__ idx) {
    int r = blockIdx.x * 256 + threadIdx.x;
    if (r >= R_) return;
    int b = r / N_;
    // 1) fp32 prefilter: top-16 of the 96 segment candidates
    float kd[RER_];
    int ki[RER_];
#pragma unroll
    for (int j = 0; j < RER_; j++) { kd[j] = 1e30f; ki[j] = 0x7fffffff; }
    const float* cdp = cd + (size_t)r * CAND_;
    const int* cip = ci + (size_t)r * CAND_;
    for (int q = 0; q < CAND_; ++q) {
        float d = cdp[q];
        int i = cip[q];
        INSERTK(RER_, kd, ki, d, i, float);
    }
    // 2) sort the 16 candidate indices ascending (odd-even network, static idx)
#pragma unroll
    for (int ph = 0; ph < RER_; ++ph) {
#pragma unroll
        for (int a = (ph & 1); a + 1 < RER_; a += 2) {
            if (ki[a] > ki[a + 1]) { int t = ki[a]; ki[a] = ki[a + 1]; ki[a + 1] = t; }
        }
    }
    // 3) fp64 exact re-rank, strict-< insertion in ascending-index order
    double kdd[9];
    int kii[9];
#pragma unroll
    for (int j = 0; j < 9; j++) { kdd[j] = 1e300; kii[j] = 0x7fffffff; }
    const double* qrow = ftp64 + (size_t)r * C_;
    double sqn = sq64[r];
#pragma unroll
    for (int t = 0; t < RER_; ++t) {
        int j = ki[t];
        const double* crow = ftp64 + ((size_t)b * N_ + j) * C_;
        double d0 = 0.0, d1 = 0.0, d2 = 0.0, d3 = 0.0;
        for (int c = 0; c < 96; c += 4) {
            d0 += qrow[c + 0] * crow[c + 0];
            d1 += qrow[c + 1] * crow[c + 1];
            d2 += qrow[c + 2] * crow[c + 2];
            d3 += qrow[c + 3] * crow[c + 3];
        }
        double dv = sqn - 2.0 * ((d0 + d1) + (d2 + d3)) + sq64[b * N_ + j];
        INSERTK(9, kdd, kii, dv, j, double);
    }
#pragma unroll
    for (int j = 0; j < 9; j++) idx[(size_t)r * 9 + j] = kii[j];
}

// ---------------- u = ft·(Wtop-Wbot) + b_edge (mode 0), v = ft·Wbot (mode 1) ----------------
__global__ __launch_bounds__(512) void k_gemm_uv(const float* __restrict__ ftc,
                                                 const float* __restrict__ We,
                                                 const float* __restrict__ beb,
                                                 float* __restrict__ out, int mode) {
    __shared__ float Wl[96 * 48];
    int tid = threadIdx.x;
    int rl = tid & 255, h = tid >> 8;
    int dbase = blockIdx.y * 48;
    for (int q = tid; q < 96 * 48; q += 512) {
        int c = q / 48, dd = q % 48;
        float w = We[(96 + c) * C2_ + dbase + dd];
        if (mode == 0) w = We[c * C2_ + dbase + dd] - w;
        Wl[c * 48 + dd] = w;
    }
    __syncthreads();
    int r = blockIdx.x * 256 + rl;
    int b = r / N_, n = r - b * N_;
    float acc[24];
#pragma unroll
    for (int i = 0; i < 24; i++) acc[i] = 0.f;
    const float* xp = ftc + (size_t)b * C_ * N_ + n;
    for (int c = 0; c < 96; ++c) {
        float xv = xp[(size_t)c * N_];
        const float4* w4 = (const float4*)&Wl[c * 48 + h * 24];
#pragma unroll
        for (int i = 0; i < 6; ++i) {
            float4 w = w4[i];
            acc[i * 4 + 0] += xv * w.x;
            acc[i * 4 + 1] += xv * w.y;
            acc[i * 4 + 2] += xv * w.z;
            acc[i * 4 + 3] += xv * w.w;
        }
    }
    int d0 = dbase + h * 24;
    float* op = out + (size_t)r * C2_ + d0;
#pragma unroll
    for (int i = 0; i < 6; ++i) {
        float4 o;
        o.x = acc[i * 4 + 0]; o.y = acc[i * 4 + 1];
        o.z = acc[i * 4 + 2]; o.w = acc[i * 4 + 3];
        if (mode == 0) {
            o.x += beb[d0 + i * 4 + 0];
            o.y += beb[d0 + i * 4 + 1];
            o.z += beb[d0 + i * 4 + 2];
            o.w += beb[d0 + i * 4 + 3];
        }
        ((float4*)op)[i] = o;
    }
}

// ---------------- edge-BN stats: e = u[n,d] + v[j,d] over all (row,k) ----------------
__global__ __launch_bounds__(192) void k_bne_stats(const float* __restrict__ u,
                                                   const float* __restrict__ v,
                                                   const int* __restrict__ idx,
                                                   float* __restrict__ partial) {
    int d = threadIdx.x;
    int row0 = blockIdx.x * 32;
    int b = row0 / N_;
    float s = 0.f, ss = 0.f;
    for (int r = 0; r < 32; ++r) {
        int row = row0 + r;
        float ud = u[(size_t)row * C2_ + d];
        const int* ip = idx + (size_t)row * 9;
#pragma unroll
        for (int k = 0; k < 9; k++) {
            int j = ip[k];
            float e = ud + v[((size_t)b * N_ + j) * C2_ + d];
            s += e;
            ss += e * e;
        }
    }
    partial[(size_t)blockIdx.x * 384 + d] = s;
    partial[(size_t)blockIdx.x * 384 + 192 + d] = ss;
}

// ---------------- edge BN+relu+max over k, then fc2 (192->96) ----------------
__global__ __launch_bounds__(192) void k_edge_fc2(const float* __restrict__ u,
                                                  const float* __restrict__ v,
                                                  const int* __restrict__ idx,
                                                  const float* __restrict__ statsE,
                                                  const float* __restrict__ ge,
                                                  const float* __restrict__ bee,
                                                  const float* __restrict__ W2,
                                                  const float* __restrict__ b2,
                                                  float* __restrict__ out2) {
    __shared__ float gl[16][C2_];
    __shared__ float g2[C_][16];
    int tid = threadIdx.x;
    int row0 = blockIdx.x * 16;
    int b = row0 / N_;
    int n0 = row0 - b * N_;
    {
        int d = tid;
        float m = statsE[d * 2], rs = statsE[d * 2 + 1];
        float ga = ge[d], bb = bee[d];
        for (int r = 0; r < 16; ++r) {
            int row = row0 + r;
            float ud = u[(size_t)row * C2_ + d];
            const int* ip = idx + (size_t)row * 9;
            float gm = 0.f;                      // relu-then-max == max with 0
#pragma unroll
            for (int k = 0; k < 9; k++) {
                int j = ip[k];
                float e = ud + v[((size_t)b * N_ + j) * C2_ + d];
                float val = ga * (e - m) * rs + bb;
                gm = fmaxf(gm, val);
            }
            gl[r][d] = gm;
        }
    }
    __syncthreads();
    {
        int rr = tid / 24;     // 0..7
        int dq = tid % 24;     // float4 column group
        for (int rep = 0; rep < 2; ++rep) {
            int r = rr + rep * 8;
            float4 acc = *(const float4*)&b2[dq * 4];
            for (int d = 0; d < C2_; ++d) {
                float gv = gl[r][d];
                float4 w = *(const float4*)&W2[d * C_ + dq * 4];
                acc.x += gv * w.x;
                acc.y += gv * w.y;
                acc.z += gv * w.z;
                acc.w += gv * w.w;
            }
            g2[dq * 4 + 0][r] = acc.x;
            g2[dq * 4 + 1][r] = acc.y;
            g2[dq * 4 + 2][r] = acc.z;
            g2[dq * 4 + 3][r] = acc.w;
        }
    }
    __syncthreads();
    for (int q = tid; q < 96 * 4; q += 192) {
        int dd = q / 4, part = q % 4;
        float4 val = *(const float4*)&g2[dd][part * 4];
        *(float4*)&out2[((size_t)b * C_ + dd) * N_ + n0 + part * 4] = val;
    }
}

// ---------------- t = bn2(out2) + x ----------------
__global__ __launch_bounds__(256) void k_bn2_add(const float* __restrict__ out2,
                                                 const float* __restrict__ x,
                                                 const float* __restrict__ stats,
                                                 const float* __restrict__ g,
                                                 const float* __restrict__ be,
                                                 float* __restrict__ t) {
    int i = blockIdx.x * 256 + threadIdx.x;
    if (i >= B_ * C_ * N_) return;
    int c = (i / N_) % C_;
    t[i] = g[c] * (out2[i] - stats[c * 2]) * stats[c * 2 + 1] + be[c] + x[i];
}

// ---------------- s = relu(sabn(t)) ----------------
__global__ __launch_bounds__(256) void k_sabn_relu(const float* __restrict__ t,
                                                   const float* __restrict__ stats,
                                                   const float* __restrict__ g,
                                                   const float* __restrict__ be,
                                                   float* __restrict__ s) {
    int i = blockIdx.x * 256 + threadIdx.x;
    if (i >= B_ * C_ * N_) return;
    int c = (i / N_) % C_;
    s[i] = fmaxf(g[c] * (t[i] - stats[c * 2]) * stats[c * 2 + 1] + be[c], 0.f);
}

// ---------------- conv 3x3 stride 2 pad 1, 96->192 ----------------
__global__ __launch_bounds__(256) void k_conv(const float* __restrict__ s,
                                              const float* __restrict__ Wd,
                                              const float* __restrict__ bd,
                                              float* __restrict__ z) {
    __shared__ float Wl[96 * 9 * 16];
    int b = blockIdx.z;
    int oc0 = blockIdx.y * 16;
    int p = blockIdx.x * 256 + threadIdx.x;
    for (int i = threadIdx.x; i < 96 * 9 * 16; i += 256) {
        int oc = i & 15;
        int icq = i >> 4;
        Wl[i] = Wd[(size_t)(oc0 + oc) * 864 + icq];
    }
    __syncthreads();
    if (p >= NO_) return;
    int oh = p / HO_, ow = p % HO_;
    float acc[16];
#pragma unroll
    for (int i = 0; i < 16; i++) acc[i] = 0.f;
    int ih0 = oh * 2 - 1, iw0 = ow * 2 - 1;
    const float* sb = s + (size_t)b * C_ * N_;
    for (int ic = 0; ic < 96; ++ic) {
        const float* sp = sb + (size_t)ic * N_;
        float in[9];
#pragma unroll
        for (int kh = 0; kh < 3; kh++) {
            int ih = ih0 + kh;
            bool okh = (unsigned)ih < 56u;
#pragma unroll
            for (int kw = 0; kw < 3; kw++) {
                int iw = iw0 + kw;
                bool ok = okh && ((unsigned)iw < 56u);
                in[kh * 3 + kw] = ok ? sp[ih * 56 + iw] : 0.f;
            }
        }
#pragma unroll
        for (int q = 0; q < 9; q++) {
            float iv = in[q];
            const float4* w4 = (const float4*)&Wl[(ic * 9 + q) * 16];
#pragma unroll
            for (int j = 0; j < 4; j++) {
                float4 w = w4[j];
                acc[j * 4 + 0] += iv * w.x;
                acc[j * 4 + 1] += iv * w.y;
                acc[j * 4 + 2] += iv * w.z;
                acc[j * 4 + 3] += iv * w.w;
            }
        }
    }
#pragma unroll
    for (int i = 0; i < 16; i++)
        z[((size_t)b * OUP_ + oc0 + i) * NO_ + p] = acc[i] + bd[oc0 + i];
}

// ---------------- out = relu(dwbn(z)) ----------------
__global__ __launch_bounds__(256) void k_out(const float* __restrict__ z,
                                             const float* __restrict__ stats,
                                             const float* __restrict__ g,
                                             const float* __restrict__ be,
                                             float* __restrict__ out) {
    int i = blockIdx.x * 256 + threadIdx.x;
    if (i >= B_ * OUP_ * NO_) return;
    int c = (i / NO_) % OUP_;
    out[i] = fmaxf(g[c] * (z[i] - stats[c * 2]) * stats[c * 2 + 1] + be[c], 0.f);
}

extern "C" void kernel_launch(void* const* d_in, const int* in_sizes, int n_in,
                              void* d_out, int out_size, void* d_ws, size_t ws_size,
                              hipStream_t stream) {
    const float* x     = (const float*)d_in[0];
    const float* W_fc1 = (const float*)d_in[1];
    const float* b_fc1 = (const float*)d_in[2];
    const float* g_bn1 = (const float*)d_in[3];
    const float* be_bn1= (const float*)d_in[4];
    const float* W_edge= (const float*)d_in[5];
    const float* b_edge= (const float*)d_in[6];
    const float* g_bne = (const float*)d_in[7];
    const float* be_bne= (const float*)d_in[8];
    const float* W_fc2 = (const float*)d_in[9];
    const float* b_fc2 = (const float*)d_in[10];
    const float* g_bn2 = (const float*)d_in[11];
    const float* be_bn2= (const float*)d_in[12];
    const float* g_sabn= (const float*)d_in[13];
    const float* be_sabn=(const float*)d_in[14];
    const float* W_dw  = (const float*)d_in[15];
    const float* b_dw  = (const float*)d_in[16];
    const float* g_dwbn= (const float*)d_in[17];
    const float* be_dwbn=(const float*)d_in[18];

    // byte-offset workspace layout with lifetime-based aliasing (~87 MB)
    char* base = (char*)d_ws;
    float*  ftc   = (float*)(base + 0);                    //  9,633,792  [bn1 -> gemms]
    float*  ftp32 = (float*)(base + 9633792);              //  9,633,792  [bn1 -> dist]
    double* ftp64 = (double*)(base + 19267584);            // 19,267,584  [bn1 -> rerank]
    double* sq64  = (double*)(base + 38535168);            //    200,704
    double* yd    = (double*)(base + 38735872);            // 19,267,584  [fc1 -> bn1]
    float*  cd    = (float*)(base + 38735872);             //  9,633,792  [dist -> merge]  (aliases yd)
    int*    ci    = (int*)(base + 48369664);               //  9,633,792  [dist -> merge]  (aliases yd hi-half)
    float*  out2  = (float*)(base + 38735872);             //  9,633,792  [edge_fc2 -> bn2] (aliases yd/cd)
    float*  zbuf  = (float*)(base + 58003456);             //  4,816,896  [conv -> out]
    int*    idx   = (int*)(base + 65228800);               //    903,168  [merge -> edge_fc2]
    float*  uu    = (float*)(base + 19267584);             // 19,267,584  [gemm -> edge_fc2] (aliases ftp64)
    float*  vv    = (float*)(base + 66131968);             // 19,267,584  [gemm -> edge_fc2]
    float*  tbuf  = (float*)(base + 9633792);              //  9,633,792  [bn2 -> sabn]  (aliases ftp32)
    float*  sbuf  = (float*)(base + 0);                    //  9,633,792  [sabn -> conv] (aliases ftc)
    float*  partial = (float*)(base + 85399552);           //  1,204,224 max
    double* partiald = (double*)(base + 85399552);         //     24,576 (same region, earlier use)
    double* stats1d = (double*)(base + 86603776);          //      1,536
    float*  statsE  = (float*)(base + 86605312);
    float*  stats2  = statsE + 384;
    float*  statsS  = stats2 + 384;
    float*  statsD  = statsS + 384;
    float*  sq32    = (float*)(base + 86611456);           //    100,352 -> ends 86,711,808

    // fc1 + BN1 (fp64 path, exact stats + features)
    k_fc1_d<<<dim3(98, 2), 512, 0, stream>>>(x, W_fc1, b_fc1, yd);
    k_stats_chan_d<<<dim3(96, 16), 256, 0, stream>>>(yd, partiald);
    k_stats_reduce_d<<<1, 256, 0, stream>>>(partiald, stats1d);
    k_bn1_apply_d<<<9408, 256, 0, stream>>>(yd, stats1d, g_bn1, be_bn1, ftc, ftp32, ftp64);
    k_sqrows_d<<<98, 256, 0, stream>>>(ftp64, sq64, sq32);

    // kNN: fp32 prefilter (top-12 per segment), fp64 re-rank of top-16 -> exact top-9 set
    k_dist_topk_f<<<dim3(13, SEG_, B_), 256, 0, stream>>>(ftp32, sq32, cd, ci);
    k_merge_rerank<<<98, 256, 0, stream>>>(cd, ci, ftp64, sq64, idx);

    // edge GEMM decomposition: u = ft·(Wtop-Wbot)+b_edge, v = ft·Wbot
    k_gemm_uv<<<dim3(98, 4), 512, 0, stream>>>(ftc, W_edge, b_edge, uu, 0);
    k_gemm_uv<<<dim3(98, 4), 512, 0, stream>>>(ftc, W_edge, b_edge, vv, 1);

    // edge BN stats, then BN+relu+max+fc2
    k_bne_stats<<<784, 192, 0, stream>>>(uu, vv, idx, partial);
    k_stats_reduce_b<<<1, 256, 0, stream>>>(partial, statsE, 192, 784, 1.0f / 225792.0f);
    k_edge_fc2<<<1568, 192, 0, stream>>>(uu, vv, idx, statsE, g_bne, be_bne, W_fc2, b_fc2, out2);

    // BN2 + shortcut
    k_stats_chan<<<dim3(96, 16), 256, 0, stream>>>(out2, partial, 96, N_, R_);
    k_stats_reduce<<<1, 256, 0, stream>>>(partial, stats2, 96, 16, 1.0f / (float)R_);
    k_bn2_add<<<9408, 256, 0, stream>>>(out2, x, stats2, g_bn2, be_bn2, tbuf);

    // sabn + relu
    k_stats_chan<<<dim3(96, 16), 256, 0, stream>>>(tbuf, partial, 96, N_, R_);
    k_stats_reduce<<<1, 256, 0, stream>>>(partial, statsS, 96, 16, 1.0f / (float)R_);
    k_sabn_relu<<<9408, 256, 0, stream>>>(tbuf, statsS, g_sabn, be_sabn, sbuf);

    // conv + dwbn + relu
    k_conv<<<dim3(4, 12, 8), 256, 0, stream>>>(sbuf, W_dw, b_dw, zbuf);
    k_stats_chan<<<dim3(192, 8), 256, 0, stream>>>(zbuf, partial, 192, NO_, 6272);
    k_stats_reduce<<<1, 256, 0, stream>>>(partial, statsD, 192, 8, 1.0f / 6272.0f);
    k_out<<<4705, 256, 0, stream>>>(zbuf, statsD, g_dwbn, be_dwbn, (float*)d_out);
}

// Round 4
// 946.796 us; speedup vs baseline: 13.2785x; 1.4829x over previous
//
#include <hip/hip_runtime.h>
#include <math.h>

#define B_   8
#define C_   96
#define C2_  192
#define N_   3136        // 56*56
#define R_   25088       // B_*N_
#define OUP_ 192
#define HO_  28
#define NO_  784         // 28*28
#define EPS_ 1e-5f
#define PSTR 200         // padded split-bf16 point stride (elements)
#define DSTR 65          // dist LDS tile stride (f32)

typedef short bf16x8 __attribute__((ext_vector_type(8)));
typedef float f32x4  __attribute__((ext_vector_type(4)));

// generic strict-< sorted insertion (static unroll)
#define INSERTK(K, kd, ki, dv, iv, T)                                       \
    if ((dv) < kd[(K)-1]) {                                                 \
        kd[(K)-1] = (dv); ki[(K)-1] = (iv);                                 \
        _Pragma("unroll")                                                   \
        for (int j = (K)-1; j >= 1; --j) {                                  \
            if (kd[j] < kd[j - 1]) {                                        \
                T td = kd[j]; kd[j] = kd[j - 1]; kd[j - 1] = td;            \
                int ti = ki[j]; ki[j] = ki[j - 1]; ki[j - 1] = ti;          \
            }                                                               \
        }                                                                   \
    }

// ---------------- fc1 (fp64 accumulate): yd[b,d,n] = sum_c x[b,c,n]*W1[c,d] + b1[d] ----------------
__global__ __launch_bounds__(512) void k_fc1_d(const float* __restrict__ x,
                                               const float* __restrict__ W1,
                                               const float* __restrict__ b1,
                                               double* __restrict__ yd) {
    __shared__ double Wl[96 * 48];
    int tid = threadIdx.x;
    int rl = tid & 255, h = tid >> 8;
    int dbase = blockIdx.y * 48;
    for (int q = tid; q < 96 * 48; q += 512) {
        int c = q / 48, dd = q % 48;
        Wl[c * 48 + dd] = (double)W1[c * 96 + dbase + dd];
    }
    __syncthreads();
    int r = blockIdx.x * 256 + rl;
    int b = r / N_;
    int n = r - b * N_;
    double acc[24];
#pragma unroll
    for (int i = 0; i < 24; i++) acc[i] = 0.0;
    const float* xp = x + (size_t)b * C_ * N_ + n;
    for (int c = 0; c < 96; ++c) {
        double xv = (double)xp[(size_t)c * N_];
        const double* w = &Wl[c * 48 + h * 24];
#pragma unroll
        for (int i = 0; i < 24; ++i) acc[i] += xv * w[i];
    }
    int d0 = dbase + h * 24;
#pragma unroll
    for (int i = 0; i < 24; i++) {
        int d = d0 + i;
        yd[((size_t)b * C_ + d) * N_ + n] = acc[i] + (double)b1[d];
    }
}

// ---------------- fp64 per-channel stats over yd ----------------
__global__ __launch_bounds__(256) void k_stats_chan_d(const double* __restrict__ src,
                                                      double* __restrict__ partial) {
    int c = blockIdx.x;
    int chunk = blockIdx.y;
    const int SPLIT = 16;
    double s = 0.0, ss = 0.0;
    for (int j = chunk * 256 + threadIdx.x; j < R_; j += SPLIT * 256) {
        int b = j / N_, n = j - b * N_;
        double v = src[((size_t)b * C_ + c) * N_ + n];
        s += v;
        ss += v * v;
    }
    __shared__ double red[8];
    for (int off = 32; off; off >>= 1) {
        s += __shfl_down(s, off, 64);
        ss += __shfl_down(ss, off, 64);
    }
    int lane = threadIdx.x & 63, w = threadIdx.x >> 6;
    if (lane == 0) { red[w * 2] = s; red[w * 2 + 1] = ss; }
    __syncthreads();
    if (threadIdx.x == 0) {
        s = red[0] + red[2] + red[4] + red[6];
        ss = red[1] + red[3] + red[5] + red[7];
        partial[(c * SPLIT + chunk) * 2] = s;
        partial[(c * SPLIT + chunk) * 2 + 1] = ss;
    }
}

__global__ void k_stats_reduce_d(const double* __restrict__ partial, double* __restrict__ stats) {
    int c = blockIdx.x * blockDim.x + threadIdx.x;
    if (c >= 96) return;
    double s = 0.0, ss = 0.0;
    for (int k = 0; k < 16; k++) {
        s += partial[(c * 16 + k) * 2];
        ss += partial[(c * 16 + k) * 2 + 1];
    }
    double m = s / (double)R_;
    double var = ss / (double)R_ - m * m;
    stats[c * 2] = m;
    stats[c * 2 + 1] = 1.0 / sqrt(var + 1e-5);
}

// ---------------- fp32 per-channel stats ----------------
__global__ __launch_bounds__(256) void k_stats_chan(const float* __restrict__ src,
                                                    float* __restrict__ partial,
                                                    int Cn, int Nsp, int total) {
    int c = blockIdx.x;
    int chunk = blockIdx.y;
    int SPLIT = gridDim.y;
    float s = 0.f, ss = 0.f;
    for (int j = chunk * 256 + threadIdx.x; j < total; j += SPLIT * 256) {
        int b = j / Nsp, n = j - b * Nsp;
        float v = src[((size_t)b * Cn + c) * Nsp + n];
        s += v;
        ss += v * v;
    }
    __shared__ float red[8];
    for (int off = 32; off; off >>= 1) {
        s += __shfl_down(s, off, 64);
        ss += __shfl_down(ss, off, 64);
    }
    int lane = threadIdx.x & 63, w = threadIdx.x >> 6;
    if (lane == 0) { red[w * 2] = s; red[w * 2 + 1] = ss; }
    __syncthreads();
    if (threadIdx.x == 0) {
        s = red[0] + red[2] + red[4] + red[6];
        ss = red[1] + red[3] + red[5] + red[7];
        partial[(c * SPLIT + chunk) * 2] = s;
        partial[(c * SPLIT + chunk) * 2 + 1] = ss;
    }
}

__global__ void k_stats_reduce(const float* __restrict__ partial, float* __restrict__ stats,
                               int Cn, int SPLIT, float invcount) {
    int c = blockIdx.x * blockDim.x + threadIdx.x;
    if (c >= Cn) return;
    float s = 0.f, ss = 0.f;
    for (int k = 0; k < SPLIT; k++) {
        s += partial[(c * SPLIT + k) * 2];
        ss += partial[(c * SPLIT + k) * 2 + 1];
    }
    float m = s * invcount;
    float var = ss * invcount - m * m;
    stats[c * 2] = m;
    stats[c * 2 + 1] = 1.0f / sqrtf(var + EPS_);
}

// parallel reduce for k_bne_stats partials: one block per channel
__global__ __launch_bounds__(256) void k_stats_reduce_b2(const float* __restrict__ partial,
                                                         float* __restrict__ stats,
                                                         float invcount) {
    int c = blockIdx.x;      // 0..191
    float s = 0.f, ss = 0.f;
    for (int k = threadIdx.x; k < 784; k += 256) {
        s  += partial[(size_t)k * 384 + c];
        ss += partial[(size_t)k * 384 + 192 + c];
    }
    __shared__ float red[8];
    for (int off = 32; off; off >>= 1) {
        s += __shfl_down(s, off, 64);
        ss += __shfl_down(ss, off, 64);
    }
    int lane = threadIdx.x & 63, w = threadIdx.x >> 6;
    if (lane == 0) { red[w * 2] = s; red[w * 2 + 1] = ss; }
    __syncthreads();
    if (threadIdx.x == 0) {
        s = red[0] + red[2] + red[4] + red[6];
        ss = red[1] + red[3] + red[5] + red[7];
        float m = s * invcount;
        float var = ss * invcount - m * m;
        stats[c * 2] = m;
        stats[c * 2 + 1] = 1.0f / sqrtf(var + EPS_);
    }
}

// ---------------- apply BN1 (fp64); emit ftc (f32 ch-major), ftp32/ftp64 (point-major) ----------------
__global__ __launch_bounds__(256) void k_bn1_apply_d(const double* __restrict__ yd,
                                                     const double* __restrict__ stats,
                                                     const float* __restrict__ g,
                                                     const float* __restrict__ be,
                                                     float* __restrict__ ftc,
                                                     float* __restrict__ ftp32,
                                                     double* __restrict__ ftp64) {
    int i = blockIdx.x * 256 + threadIdx.x;
    if (i >= B_ * C_ * N_) return;
    int n = i % N_;
    int bc = i / N_;
    int c = bc % C_;
    int b = bc / C_;
    double m = stats[c * 2], rs = stats[c * 2 + 1];
    double v = (double)g[c] * (yd[i] - m) * rs + (double)be[c];
    float vf = (float)v;
    ftc[i] = vf;
    size_t pp = ((size_t)b * N_ + n) * C_ + c;
    ftp32[pp] = vf;
    ftp64[pp] = v;
}

// ---------------- row squared norms: fp64 exact + fp32 copy ----------------
__global__ __launch_bounds__(256) void k_sqrows_d(const double* __restrict__ ftp64,
                                                  double* __restrict__ sq64,
                                                  float* __restrict__ sq32) {
    int r = blockIdx.x * 256 + threadIdx.x;
    if (r >= R_) return;
    const double* p = ftp64 + (size_t)r * C_;
    double s = 0.0;
    for (int q = 0; q < 96; q++) s += p[q] * p[q];
    sq64[r] = s;
    sq32[r] = (float)s;
}

// ---------------- split ft into bf16 hi/lo pairs (point-major, padded stride) ----------------
__global__ __launch_bounds__(256) void k_split(const float* __restrict__ ftp32,
                                               unsigned short* __restrict__ fsp) {
    int t = blockIdx.x * 256 + threadIdx.x;
    if (t >= R_ * 12) return;
    int p = t / 12, g = t % 12;
    const float* src = ftp32 + (size_t)p * C_ + g * 8;
    unsigned short hi[8], lo[8];
#pragma unroll
    for (int j = 0; j < 8; ++j) {
        float x = src[j];
        unsigned u = __float_as_uint(x);
        unsigned r = (u + 0x7fffu + ((u >> 16) & 1u)) >> 16;       // RNE to bf16
        float hf = __uint_as_float(r << 16);
        hi[j] = (unsigned short)r;
        float res = x - hf;                                        // exact
        unsigned u2 = __float_as_uint(res);
        unsigned r2 = (u2 + 0x7fffu + ((u2 >> 16) & 1u)) >> 16;
        lo[j] = (unsigned short)r2;
    }
    unsigned short* dh = fsp + (size_t)p * PSTR + g * 8;
    unsigned short* dl = dh + 96;
    *(ushort4*)dh       = *(ushort4*)&hi[0];
    *(ushort4*)(dh + 4) = *(ushort4*)&hi[4];
    *(ushort4*)dl       = *(ushort4*)&lo[0];
    *(ushort4*)(dl + 4) = *(ushort4*)&lo[4];
}

// ---------------- split-bf16 MFMA distance + per-row top-16 pool ----------------
// block: 32 query rows x all 3136 candidates (49 chunks of 64), 4 waves.
// dot = hi.hi + hi.lo + lo.hi  (K-extended to 288 = 9 MFMA slices)
__global__ __launch_bounds__(256) void k_dist_mfma(const unsigned short* __restrict__ fsp,
                                                   const float* __restrict__ sq32,
                                                   int* __restrict__ poolI) {
    __shared__ __align__(16) char lds_raw[47232];
    unsigned short* Al = (unsigned short*)lds_raw;            // 32 x 200
    unsigned short* Bl = (unsigned short*)(lds_raw + 12800);  // 64 x 200
    float* distl = (float*)(lds_raw + 38400);                 // 32 x 65
    float* sqtl  = (float*)(lds_raw + 46720);                 // 64
    float* mgD = (float*)lds_raw;                             // merge alias: 32*8*16 f32
    int*   mgI = (int*)(lds_raw + 16384);

    int b = blockIdx.y;
    int r0 = blockIdx.x * 32;
    int tid = threadIdx.x;
    int w = tid >> 6, l = tid & 63;

    // stage A tile (32 rows x 400 B, contiguous)
    {
        const uint4* src = (const uint4*)(fsp + ((size_t)b * N_ + r0) * PSTR);
        uint4* dst = (uint4*)Al;
        for (int i = tid; i < 32 * 25; i += 256) dst[i] = src[i];
    }
    __syncthreads();

    int rt = w & 1;          // row tile of this wave
    int cg = w >> 1;         // col-pair group
    bf16x8 Af[6];            // 3 hi slices + 3 lo slices, K-chunks of this lane
    {
        int row = rt * 16 + (l & 15);
        int koff = (l >> 4) * 8;
#pragma unroll
        for (int s = 0; s < 6; ++s)
            Af[s] = *(const bf16x8*)&Al[row * PSTR + s * 32 + koff];
    }

    float kd[16]; int ki[16];
#pragma unroll
    for (int j = 0; j < 16; ++j) { kd[j] = 1e30f; ki[j] = 0x7fffffff; }
    int srow = tid & 31, sq = tid >> 5;   // selection mapping (conflict-free reads)

    const int Asel[9] = {0, 1, 2, 0, 1, 2, 3, 4, 5};
    const int Bsel[9] = {0, 1, 2, 3, 4, 5, 0, 1, 2};

    for (int ch = 0; ch < 49; ++ch) {
        int c0 = ch * 64;
        __syncthreads();   // previous selection finished before B overwrite
        {
            const uint4* src = (const uint4*)(fsp + ((size_t)b * N_ + c0) * PSTR);
            uint4* dst = (uint4*)Bl;
            for (int i = tid; i < 64 * 25; i += 256) dst[i] = src[i];
        }
        if (tid < 64) sqtl[tid] = sq32[b * N_ + c0 + tid];
        __syncthreads();
#pragma unroll
        for (int ct = 0; ct < 2; ++ct) {
            int colr = cg * 32 + ct * 16 + (l & 15);
            int koff = (l >> 4) * 8;
            bf16x8 Bf[6];
#pragma unroll
            for (int s = 0; s < 6; ++s)
                Bf[s] = *(const bf16x8*)&Bl[colr * PSTR + s * 32 + koff];
            f32x4 acc = {0.f, 0.f, 0.f, 0.f};
#pragma unroll
            for (int s = 0; s < 9; ++s)
                acc = __builtin_amdgcn_mfma_f32_16x16x32_bf16(Af[Asel[s]], Bf[Bsel[s]], acc, 0, 0, 0);
            float sv = sqtl[colr];
            int rowb = rt * 16 + (l >> 4) * 4;       // C/D: col=lane&15, row=(lane>>4)*4+reg
#pragma unroll
            for (int j = 0; j < 4; ++j)
                distl[(rowb + j) * DSTR + colr] = sv - 2.f * acc[j];
        }
        __syncthreads();
        // selection: 8 threads per row, each scans cols q+8i (ascending index)
#pragma unroll
        for (int i = 0; i < 8; ++i) {
            int col = sq + 8 * i;
            float d = distl[srow * DSTR + col];
            int gi = c0 + col;
            INSERTK(16, kd, ki, d, gi, float);
        }
    }
    __syncthreads();
    // merge 8 partial top-16 per row -> top-16 pool, sorted by index
#pragma unroll
    for (int j = 0; j < 16; ++j) {
        mgD[(srow * 8 + sq) * 16 + j] = kd[j];
        mgI[(srow * 8 + sq) * 16 + j] = ki[j];
    }
    __syncthreads();
    if (tid < 32) {
        float fd[16]; int fi[16];
#pragma unroll
        for (int j = 0; j < 16; ++j) { fd[j] = 1e30f; fi[j] = 0x7fffffff; }
        for (int qq = 0; qq < 8; ++qq) {
#pragma unroll
            for (int j = 0; j < 16; ++j) {
                float d = mgD[(tid * 8 + qq) * 16 + j];
                int gi = mgI[(tid * 8 + qq) * 16 + j];
                INSERTK(16, fd, fi, d, gi, float);
            }
        }
#pragma unroll
        for (int ph = 0; ph < 16; ++ph) {
#pragma unroll
            for (int a = (ph & 1); a + 1 < 16; a += 2) {
                if (fi[a] > fi[a + 1]) { int t = fi[a]; fi[a] = fi[a + 1]; fi[a + 1] = t; }
            }
        }
        int* op = poolI + ((size_t)b * N_ + r0 + tid) * 16;
#pragma unroll
        for (int j = 0; j < 16; ++j) op[j] = fi[j];
    }
}

// ---------------- fp64 exact re-rank of the 16-pool -> stable top-9 ----------------
// one wave per row: 16 candidates x 4 lanes each (24 contiguous channels per lane)
__global__ __launch_bounds__(256) void k_rerank_d(const int* __restrict__ poolI,
                                                  const double* __restrict__ ftp64,
                                                  const double* __restrict__ sq64,
                                                  int* __restrict__ idx) {
    int tid = threadIdx.x;
    int wv = tid >> 6, l = tid & 63;
    int rr = blockIdx.x * 4 + wv;
    int b = rr / N_;
    int c = l >> 2, e = l & 3;
    int ji = poolI[(size_t)rr * 16 + c];
    const double* qb = ftp64 + (size_t)rr * C_;
    const double* cb = ftp64 + ((size_t)b * N_ + ji) * C_;
    double part = 0.0;
#pragma unroll
    for (int k = 0; k < 24; ++k) part += qb[e * 24 + k] * cb[e * 24 + k];
    part += __shfl_xor(part, 1, 64);
    part += __shfl_xor(part, 2, 64);
    double dv = sq64[rr] - 2.0 * part + sq64[(size_t)b * N_ + ji];
    double kdd[9]; int kii[9];
#pragma unroll
    for (int j = 0; j < 9; ++j) { kdd[j] = 1e300; kii[j] = 0x7fffffff; }
    for (int cc = 0; cc < 16; ++cc) {          // pool is index-ascending
        double d = __shfl(dv, cc * 4, 64);
        int jv = __shfl(ji, cc * 4, 64);
        INSERTK(9, kdd, kii, d, jv, double);
    }
    if (l < 9) idx[(size_t)rr * 9 + l] = kii[l];
}

// ---------------- u = ft·(Wtop-Wbot) + b_edge (mode 0), v = ft·Wbot (mode 1) ----------------
__global__ __launch_bounds__(512) void k_gemm_uv(const float* __restrict__ ftc,
                                                 const float* __restrict__ We,
                                                 const float* __restrict__ beb,
                                                 float* __restrict__ out, int mode) {
    __shared__ float Wl[96 * 48];
    int tid = threadIdx.x;
    int rl = tid & 255, h = tid >> 8;
    int dbase = blockIdx.y * 48;
    for (int q = tid; q < 96 * 48; q += 512) {
        int c = q / 48, dd = q % 48;
        float w = We[(96 + c) * C2_ + dbase + dd];
        if (mode == 0) w = We[c * C2_ + dbase + dd] - w;
        Wl[c * 48 + dd] = w;
    }
    __syncthreads();
    int r = blockIdx.x * 256 + rl;
    int b = r / N_, n = r - b * N_;
    float acc[24];
#pragma unroll
    for (int i = 0; i < 24; i++) acc[i] = 0.f;
    const float* xp = ftc + (size_t)b * C_ * N_ + n;
    for (int c = 0; c < 96; ++c) {
        float xv = xp[(size_t)c * N_];
        const float4* w4 = (const float4*)&Wl[c * 48 + h * 24];
#pragma unroll
        for (int i = 0; i < 6; ++i) {
            float4 w = w4[i];
            acc[i * 4 + 0] += xv * w.x;
            acc[i * 4 + 1] += xv * w.y;
            acc[i * 4 + 2] += xv * w.z;
            acc[i * 4 + 3] += xv * w.w;
        }
    }
    int d0 = dbase + h * 24;
    float* op = out + (size_t)r * C2_ + d0;
#pragma unroll
    for (int i = 0; i < 6; ++i) {
        float4 o;
        o.x = acc[i * 4 + 0]; o.y = acc[i * 4 + 1];
        o.z = acc[i * 4 + 2]; o.w = acc[i * 4 + 3];
        if (mode == 0) {
            o.x += beb[d0 + i * 4 + 0];
            o.y += beb[d0 + i * 4 + 1];
            o.z += beb[d0 + i * 4 + 2];
            o.w += beb[d0 + i * 4 + 3];
        }
        ((float4*)op)[i] = o;
    }
}

// ---------------- edge-BN stats: e = u[n,d] + v[j,d] over all (row,k) ----------------
__global__ __launch_bounds__(192) void k_bne_stats(const float* __restrict__ u,
                                                   const float* __restrict__ v,
                                                   const int* __restrict__ idx,
                                                   float* __restrict__ partial) {
    int d = threadIdx.x;
    int row0 = blockIdx.x * 32;
    int b = row0 / N_;
    float s = 0.f, ss = 0.f;
    for (int r = 0; r < 32; ++r) {
        int row = row0 + r;
        float ud = u[(size_t)row * C2_ + d];
        const int* ip = idx + (size_t)row * 9;
#pragma unroll
        for (int k = 0; k < 9; k++) {
            int j = ip[k];
            float e = ud + v[((size_t)b * N_ + j) * C2_ + d];
            s += e;
            ss += e * e;
        }
    }
    partial[(size_t)blockIdx.x * 384 + d] = s;
    partial[(size_t)blockIdx.x * 384 + 192 + d] = ss;
}

// ---------------- edge BN+relu+max over k, then fc2 (192->96) ----------------
__global__ __launch_bounds__(192) void k_edge_fc2(const float* __restrict__ u,
                                                  const float* __restrict__ v,
                                                  const int* __restrict__ idx,
                                                  const float* __restrict__ statsE,
                                                  const float* __restrict__ ge,
                                                  const float* __restrict__ bee,
                                                  const float* __restrict__ W2,
                                                  const float* __restrict__ b2,
                                                  float* __restrict__ out2) {
    __shared__ float gl[16][C2_];
    __shared__ float g2[C_][16];
    int tid = threadIdx.x;
    int row0 = blockIdx.x * 16;
    int b = row0 / N_;
    int n0 = row0 - b * N_;
    {
        int d = tid;
        float m = statsE[d * 2], rs = statsE[d * 2 + 1];
        float ga = ge[d], bb = bee[d];
        for (int r = 0; r < 16; ++r) {
            int row = row0 + r;
            float ud = u[(size_t)row * C2_ + d];
            const int* ip = idx + (size_t)row * 9;
            float gm = 0.f;                      // relu-then-max == max with 0
#pragma unroll
            for (int k = 0; k < 9; k++) {
                int j = ip[k];
                float e = ud + v[((size_t)b * N_ + j) * C2_ + d];
                float val = ga * (e - m) * rs + bb;
                gm = fmaxf(gm, val);
            }
            gl[r][d] = gm;
        }
    }
    __syncthreads();
    {
        int rr = tid / 24;
        int dq = tid % 24;
        for (int rep = 0; rep < 2; ++rep) {
            int r = rr + rep * 8;
            float4 acc = *(const float4*)&b2[dq * 4];
            for (int d = 0; d < C2_; ++d) {
                float gv = gl[r][d];
                float4 w = *(const float4*)&W2[d * C_ + dq * 4];
                acc.x += gv * w.x;
                acc.y += gv * w.y;
                acc.z += gv * w.z;
                acc.w += gv * w.w;
            }
            g2[dq * 4 + 0][r] = acc.x;
            g2[dq * 4 + 1][r] = acc.y;
            g2[dq * 4 + 2][r] = acc.z;
            g2[dq * 4 + 3][r] = acc.w;
        }
    }
    __syncthreads();
    for (int q = tid; q < 96 * 4; q += 192) {
        int dd = q / 4, part = q % 4;
        float4 val = *(const float4*)&g2[dd][part * 4];
        *(float4*)&out2[((size_t)b * C_ + dd) * N_ + n0 + part * 4] = val;
    }
}

// ---------------- t = bn2(out2) + x ----------------
__global__ __launch_bounds__(256) void k_bn2_add(const float* __restrict__ out2,
                                                 const float* __restrict__ x,
                                                 const float* __restrict__ stats,
                                                 const float* __restrict__ g,
                                                 const float* __restrict__ be,
                                                 float* __restrict__ t) {
    int i = blockIdx.x * 256 + threadIdx.x;
    if (i >= B_ * C_ * N_) return;
    int c = (i / N_) % C_;
    t[i] = g[c] * (out2[i] - stats[c * 2]) * stats[c * 2 + 1] + be[c] + x[i];
}

// ---------------- s = relu(sabn(t)) ----------------
__global__ __launch_bounds__(256) void k_sabn_relu(const float* __restrict__ t,
                                                   const float* __restrict__ stats,
                                                   const float* __restrict__ g,
                                                   const float* __restrict__ be,
                                                   float* __restrict__ s) {
    int i = blockIdx.x * 256 + threadIdx.x;
    if (i >= B_ * C_ * N_) return;
    int c = (i / N_) % C_;
    s[i] = fmaxf(g[c] * (t[i] - stats[c * 2]) * stats[c * 2 + 1] + be[c], 0.f);
}

// ---------------- conv 3x3 stride 2 pad 1, 96->192 ----------------
__global__ __launch_bounds__(256) void k_conv(const float* __restrict__ s,
                                              const float* __restrict__ Wd,
                                              const float* __restrict__ bd,
                                              float* __restrict__ z) {
    __shared__ float Wl[96 * 9 * 16];
    int b = blockIdx.z;
    int oc0 = blockIdx.y * 16;
    int p = blockIdx.x * 256 + threadIdx.x;
    for (int i = threadIdx.x; i < 96 * 9 * 16; i += 256) {
        int oc = i & 15;
        int icq = i >> 4;
        Wl[i] = Wd[(size_t)(oc0 + oc) * 864 + icq];
    }
    __syncthreads();
    if (p >= NO_) return;
    int oh = p / HO_, ow = p % HO_;
    float acc[16];
#pragma unroll
    for (int i = 0; i < 16; i++) acc[i] = 0.f;
    int ih0 = oh * 2 - 1, iw0 = ow * 2 - 1;
    const float* sb = s + (size_t)b * C_ * N_;
    for (int ic = 0; ic < 96; ++ic) {
        const float* sp = sb + (size_t)ic * N_;
        float in[9];
#pragma unroll
        for (int kh = 0; kh < 3; kh++) {
            int ih = ih0 + kh;
            bool okh = (unsigned)ih < 56u;
#pragma unroll
            for (int kw = 0; kw < 3; kw++) {
                int iw = iw0 + kw;
                bool ok = okh && ((unsigned)iw < 56u);
                in[kh * 3 + kw] = ok ? sp[ih * 56 + iw] : 0.f;
            }
        }
#pragma unroll
        for (int q = 0; q < 9; q++) {
            float iv = in[q];
            const float4* w4 = (const float4*)&Wl[(ic * 9 + q) * 16];
#pragma unroll
            for (int j = 0; j < 4; j++) {
                float4 w = w4[j];
                acc[j * 4 + 0] += iv * w.x;
                acc[j * 4 + 1] += iv * w.y;
                acc[j * 4 + 2] += iv * w.z;
                acc[j * 4 + 3] += iv * w.w;
            }
        }
    }
#pragma unroll
    for (int i = 0; i < 16; i++)
        z[((size_t)b * OUP_ + oc0 + i) * NO_ + p] = acc[i] + bd[oc0 + i];
}

// ---------------- out = relu(dwbn(z)) ----------------
__global__ __launch_bounds__(256) void k_out(const float* __restrict__ z,
                                             const float* __restrict__ stats,
                                             const float* __restrict__ g,
                                             const float* __restrict__ be,
                                             float* __restrict__ out) {
    int i = blockIdx.x * 256 + threadIdx.x;
    if (i >= B_ * OUP_ * NO_) return;
    int c = (i / NO_) % OUP_;
    out[i] = fmaxf(g[c] * (z[i] - stats[c * 2]) * stats[c * 2 + 1] + be[c], 0.f);
}

extern "C" void kernel_launch(void* const* d_in, const int* in_sizes, int n_in,
                              void* d_out, int out_size, void* d_ws, size_t ws_size,
                              hipStream_t stream) {
    const float* x     = (const float*)d_in[0];
    const float* W_fc1 = (const float*)d_in[1];
    const float* b_fc1 = (const float*)d_in[2];
    const float* g_bn1 = (const float*)d_in[3];
    const float* be_bn1= (const float*)d_in[4];
    const float* W_edge= (const float*)d_in[5];
    const float* b_edge= (const float*)d_in[6];
    const float* g_bne = (const float*)d_in[7];
    const float* be_bne= (const float*)d_in[8];
    const float* W_fc2 = (const float*)d_in[9];
    const float* b_fc2 = (const float*)d_in[10];
    const float* g_bn2 = (const float*)d_in[11];
    const float* be_bn2= (const float*)d_in[12];
    const float* g_sabn= (const float*)d_in[13];
    const float* be_sabn=(const float*)d_in[14];
    const float* W_dw  = (const float*)d_in[15];
    const float* b_dw  = (const float*)d_in[16];
    const float* g_dwbn= (const float*)d_in[17];
    const float* be_dwbn=(const float*)d_in[18];

    // byte-offset workspace layout with lifetime-based aliasing (~74 MB)
    char* base = (char*)d_ws;
    float*  ftc   = (float*)(base + 0);                    //  9,633,792  [bn1 -> gemm_uv]; then sbuf
    float*  ftp32 = (float*)(base + 9633792);              //  9,633,792  [bn1 -> split];   then tbuf
    double* ftp64 = (double*)(base + 19267584);            // 19,267,584  [bn1 -> rerank];  then uu
    double* sq64  = (double*)(base + 38535168);            //    200,704
    double* yd    = (double*)(base + 38735872);            // 19,267,584  [fc1 -> bn1]
    unsigned short* fsp = (unsigned short*)(base + 38735872); // 10,035,200 [split -> dist] (aliases yd)
    float*  out2  = (float*)(base + 38735872);             //  9,633,792  [edge_fc2 -> bn2] (aliases fsp)
    float*  zbuf  = (float*)(base + 48771072);             //  4,816,896  [conv -> out]
    int*    poolI = (int*)(base + 53587968);               //  1,605,632  [dist -> rerank]
    int*    idx   = (int*)(base + 55193600);               //    903,168  [rerank -> edge]
    float*  uu    = (float*)(base + 19267584);             // 19,267,584  [gemm -> edge_fc2] (aliases ftp64, after rerank)
    float*  vv    = (float*)(base + 56096768);             // 19,267,584  [gemm -> edge_fc2]
    float*  tbuf  = (float*)(base + 9633792);              //  [bn2 -> sabn]  (aliases ftp32)
    float*  sbuf  = (float*)(base + 0);                    //  [sabn -> conv] (aliases ftc)
    float*  partial = (float*)(base + 75364352);           //  1,204,224 max
    double* partiald = (double*)(base + 75364352);         //     24,576 (earlier use, same region)
    double* stats1d = (double*)(base + 76568576);
    float*  statsE  = (float*)(base + 76570112);
    float*  stats2  = (float*)(base + 76571648);
    float*  statsS  = (float*)(base + 76573184);
    float*  statsD  = (float*)(base + 76574720);
    float*  sq32    = (float*)(base + 76576256);           //    100,352 -> ends 76,676,608

    // fc1 + BN1 (fp64 path, exact stats + features)
    k_fc1_d<<<dim3(98, 2), 512, 0, stream>>>(x, W_fc1, b_fc1, yd);
    k_stats_chan_d<<<dim3(96, 16), 256, 0, stream>>>(yd, partiald);
    k_stats_reduce_d<<<1, 256, 0, stream>>>(partiald, stats1d);
    k_bn1_apply_d<<<9408, 256, 0, stream>>>(yd, stats1d, g_bn1, be_bn1, ftc, ftp32, ftp64);
    k_sqrows_d<<<98, 256, 0, stream>>>(ftp64, sq64, sq32);

    // kNN: split-bf16 MFMA distances + per-row top-16 pool, fp64 re-rank -> exact top-9 set
    k_split<<<1176, 256, 0, stream>>>(ftp32, fsp);
    k_dist_mfma<<<dim3(98, B_), 256, 0, stream>>>(fsp, sq32, poolI);
    k_rerank_d<<<6272, 256, 0, stream>>>(poolI, ftp64, sq64, idx);

    // edge GEMM decomposition: u = ft·(Wtop-Wbot)+b_edge, v = ft·Wbot  (uu overwrites ftp64 after rerank)
    k_gemm_uv<<<dim3(98, 4), 512, 0, stream>>>(ftc, W_edge, b_edge, uu, 0);
    k_gemm_uv<<<dim3(98, 4), 512, 0, stream>>>(ftc, W_edge, b_edge, vv, 1);

    // edge BN stats, then BN+relu+max+fc2
    k_bne_stats<<<784, 192, 0, stream>>>(uu, vv, idx, partial);
    k_stats_reduce_b2<<<192, 256, 0, stream>>>(partial, statsE, 1.0f / 225792.0f);
    k_edge_fc2<<<1568, 192, 0, stream>>>(uu, vv, idx, statsE, g_bne, be_bne, W_fc2, b_fc2, out2);

    // BN2 + shortcut
    k_stats_chan<<<dim3(96, 16), 256, 0, stream>>>(out2, partial, 96, N_, R_);
    k_stats_reduce<<<1, 256, 0, stream>>>(partial, stats2, 96, 16, 1.0f / (float)R_);
    k_bn2_add<<<9408, 256, 0, stream>>>(out2, x, stats2, g_bn2, be_bn2, tbuf);

    // sabn + relu
    k_stats_chan<<<dim3(96, 16), 256, 0, stream>>>(tbuf, partial, 96, N_, R_);
    k_stats_reduce<<<1, 256, 0, stream>>>(partial, statsS, 96, 16, 1.0f / (float)R_);
    k_sabn_relu<<<9408, 256, 0, stream>>>(tbuf, statsS, g_sabn, be_sabn, sbuf);

    // conv + dwbn + relu
    k_conv<<<dim3(4, 12, 8), 256, 0, stream>>>(sbuf, W_dw, b_dw, zbuf);
    k_stats_chan<<<dim3(192, 8), 256, 0, stream>>>(zbuf, partial, 192, NO_, 6272);
    k_stats_reduce<<<1, 256, 0, stream>>>(partial, statsD, 192, 8, 1.0f / 6272.0f);
    k_out<<<4705, 256, 0, stream>>>(zbuf, statsD, g_dwbn, be_dwbn, (float*)d_out);
}